// Round 4
// baseline (394.072 us; speedup 1.0000x reference)
//
#include <hip/hip_runtime.h>
#include <hip/hip_bf16.h>

// MultiScaleAttentionPE — MI355X round 4
// bf16 pe intermediates + precomputed f0 (bf16) + double-buffered LDS MFMA
// level GEMM with one barrier per K-tile and register prefetch.

typedef __hip_bfloat16 bf16;
typedef unsigned short ushort_t;
typedef __attribute__((ext_vector_type(8))) short short8;
typedef __attribute__((ext_vector_type(4))) float float4v;

#define cN0 65536
#define cN1 16384
#define cN2 4096
#define cN3 1024
#define cN4 256

__device__ __forceinline__ float b2f(bf16 v) { return __bfloat162float(v); }
__device__ __forceinline__ ushort_t f2b(float v) {
    union { float f; unsigned u; } x; x.f = v;
    unsigned r = x.u + 0x7FFF + ((x.u >> 16) & 1);
    return (ushort_t)(r >> 16);
}
__device__ __forceinline__ float lo2f(unsigned u) { union { unsigned x; float f; } c; c.x = u << 16; return c.f; }
__device__ __forceinline__ float hi2f(unsigned u) { union { unsigned x; float f; } c; c.x = u & 0xffff0000u; return c.f; }
__device__ __forceinline__ unsigned pk2(float a, float b) {
    return (unsigned)f2b(a) | ((unsigned)f2b(b) << 16);
}

// ---------------- dtype detect (bf16 vs fp32 storage) ----------------
__global__ void detect_kernel(const unsigned short* __restrict__ raw, int* __restrict__ flag) {
    __shared__ int bad;
    if (threadIdx.x == 0) bad = 0;
    __syncthreads();
    for (int i = threadIdx.x; i < 1024; i += 256) {
        int e = (raw[i] >> 7) & 0xFF;
        if (e >= 138) atomicOr(&bad, 1);
    }
    __syncthreads();
    if (threadIdx.x == 0) flag[0] = bad ? 1 : 0;
}

// ---------------- canonicalize small float tensors to fp32 ----------------
// order: xyz(196608), Wall(768), ball(256), [W,b]x5 (768+256 each), pb x5 (256)
struct CanonArgs { const void* src[18]; };

__global__ void canon_kernel(CanonArgs a, const int* __restrict__ flag, float* __restrict__ dst) {
    const int sizes[18] = {196608, 768, 256,
                           768, 256, 768, 256, 768, 256, 768, 256, 768, 256,
                           256, 256, 256, 256, 256};
    int fp32 = flag[0];
    int gid = blockIdx.x * 256 + threadIdx.x;
    int off = 0;
#pragma unroll
    for (int s = 0; s < 18; ++s) {
        int n = sizes[s];
        if (gid >= off && gid < off + n) {
            int local = gid - off;
            float v = fp32 ? ((const float*)a.src[s])[local]
                           : b2f(((const bf16*)a.src[s])[local]);
            dst[gid] = v;
        }
        off += n;
    }
}

// ---------------- P -> P^T bf16 (tiled transpose, raw dtype input) ----------------
struct PtArgs { const void* P[5]; };

__global__ void prep_pt(PtArgs a, const int* __restrict__ flag, ushort_t* __restrict__ PTb) {
    __shared__ ushort_t t[64 * 68];
    int level = blockIdx.x, kb = blockIdx.y, nb = blockIdx.z;
    int fp32 = flag[0];
    const void* P = a.P[level];
    int kk = threadIdx.x >> 2, j0 = (threadIdx.x & 3) * 16;
    int k = kb * 64 + kk;
#pragma unroll
    for (int j = 0; j < 16; ++j) {
        int n = nb * 64 + j0 + j;
        float v = fp32 ? ((const float*)P)[(size_t)k * 256 + n]
                       : b2f(((const bf16*)P)[(size_t)k * 256 + n]);
        t[kk * 68 + j0 + j] = f2b(v);     // exact round-trip when src is bf16
    }
    __syncthreads();
    int nn = threadIdx.x >> 2, kg = (threadIdx.x & 3) * 16;
    ushort_t* dst = PTb + (size_t)level * 131072 + (size_t)(nb * 64 + nn) * 512 + kb * 64 + kg;
#pragma unroll
    for (int j = 0; j < 16; ++j) dst[j] = t[(kg + j) * 68 + nn];
}

// ---------------- f0 = xyz0 @ Wall + ball, bf16 [N0][256] ----------------
__global__ void f0_prep(const float* __restrict__ xyzf, const float* __restrict__ Wallf,
                        const float* __restrict__ ballf, ushort_t* __restrict__ f0B) {
    int c = threadIdx.x;
    float w0 = Wallf[c], w1 = Wallf[256 + c], w2 = Wallf[512 + c], bb = ballf[c];
    int r0 = blockIdx.x * 32;
    for (int r = r0; r < r0 + 32; ++r) {
        float x = xyzf[3 * r], y = xyzf[3 * r + 1], z = xyzf[3 * r + 2];
        float v = fmaf(z, w2, fmaf(y, w1, x * w0)) + bb;
        f0B[(size_t)r * 256 + c] = f2b(v);
    }
}

// ---------------- cls4 = column-max of f0[:256] (bf16; RNE is monotone) ----------------
__global__ void cls4_kernel(const ushort_t* __restrict__ f0B, ushort_t* __restrict__ cls4B) {
    int c = threadIdx.x;
    float best = -3.402823466e38f;
    ushort_t bb = 0;
    for (int r = 0; r < 256; ++r) {
        ushort_t s = f0B[r * 256 + c];
        float v = lo2f((unsigned)s);
        if (v > best) { best = v; bb = s; }
    }
    cls4B[c] = bb;
}

// ---------------- 1-NN argmin (fp32-exact, reference op order) ----------------
__global__ void nn_kernel(const float* __restrict__ xyzf, const int* __restrict__ idxQ,
                          const int* __restrict__ idxR, int nR, int* __restrict__ outK) {
    __shared__ __align__(16) float4 ref4[1024];
    __shared__ float redD[256];
    __shared__ int redI[256];
    int tid = threadIdx.x;
    int part = tid >> 6;
    int q = blockIdx.x * 64 + (tid & 63);
    int qi = idxQ[q];
    float qx = xyzf[3 * qi + 0];
    float qy = xyzf[3 * qi + 1];
    float qz = xyzf[3 * qi + 2];
    float q2 = (qx * qx + qy * qy) + qz * qz;
    float best = 3.402823466e38f;
    int bi = 0;
    for (int base = 0; base < nR; base += 1024) {
        int nt = min(1024, nR - base);
        __syncthreads();
        for (int t = tid; t < nt; t += 256) {
            int ri = idxR[base + t];
            float x = xyzf[3 * ri + 0];
            float y = xyzf[3 * ri + 1];
            float z = xyzf[3 * ri + 2];
            ref4[t] = make_float4(x, y, z, (x * x + y * y) + z * z);
        }
        __syncthreads();
        int seg = nt >> 2;
        int s0 = part * seg;
        for (int t = 0; t < seg; ++t) {
            float4 rp = ref4[s0 + t];
            float dot = (qx * rp.x + qy * rp.y) + qz * rp.z;
            float d = (q2 - 2.0f * dot) + rp.w;
            if (d < best) { best = d; bi = base + s0 + t; }
        }
    }
    redD[tid] = best;
    redI[tid] = bi;
    __syncthreads();
    if (part == 0) {
#pragma unroll
        for (int p = 1; p < 4; ++p) {
            float d = redD[tid + p * 64];
            int i2 = redI[tid + p * 64];
            if (d < best || (d == best && i2 < bi)) { best = d; bi = i2; }
        }
        outK[q] = bi;
    }
}

// ---------------- MFMA level kernel (double-buffered, 1 barrier/kt) ----------------
// Block: 128 rows x 256 cols, 512 threads (8 waves of 64x64).
// h row (K=512): [ peB[k_i] + dxyz_i @ W + b ; f0B[row] ], bf16.
__global__ __launch_bounds__(512, 4) void level_mfma(
    const float* __restrict__ xyzf,
    const ushort_t* __restrict__ peB,
    const ushort_t* __restrict__ f0B,
    const int* __restrict__ kmap,
    const int* __restrict__ idxQ,
    const int* __restrict__ idxR,
    const float* __restrict__ W, const float* __restrict__ bv,
    const ushort_t* __restrict__ PT, const float* __restrict__ pb,
    const int* __restrict__ flag, void* __restrict__ outv, size_t out_off,
    ushort_t* __restrict__ peOut) {
    __shared__ float Wl[768], bl[256];
    __shared__ __align__(16) ushort_t A_lds[2 * 128 * 40];  // [buf][row][k] stride 40
    __shared__ __align__(16) ushort_t B_lds[2 * 256 * 40];  // [buf][col][k] stride 40

    int tid = threadIdx.x;
    int row0 = blockIdx.x * 128;
    int fp32out = flag[0];

    for (int i = tid; i < 768; i += 512) Wl[i] = W[i];
    if (tid < 256) bl[tid] = bv[tid];

    // per-thread A positions: rows r1, r1+64; k-columns g4..g4+3 per tile
    int r1 = tid >> 3;
    int g4 = (tid & 7) * 4;
    int rows2[2] = { r1, r1 + 64 };
    float dxx[2], dyy[2], dzz[2];
    int kI[2];
#pragma unroll
    for (int i = 0; i < 2; ++i) {
        int row = row0 + rows2[i];
        int k = kmap ? kmap[row] : 0;
        kI[i] = k;
        float qx, qy, qz;
        if (idxQ) {
            int qi = idxQ[row];
            qx = xyzf[3 * qi]; qy = xyzf[3 * qi + 1]; qz = xyzf[3 * qi + 2];
        } else {
            qx = xyzf[3 * row]; qy = xyzf[3 * row + 1]; qz = xyzf[3 * row + 2];
        }
        float rx = 0.f, ry = 0.f, rz = 0.f;
        if (idxR) {
            int ri = idxR[k];
            rx = xyzf[3 * ri]; ry = xyzf[3 * ri + 1]; rz = xyzf[3 * ri + 2];
        }
        dxx[i] = qx - rx; dyy[i] = qy - ry; dzz[i] = qz - rz;
    }
    // per-thread B positions
    int bn[2] = { tid >> 2, (tid + 512) >> 2 };
    int bo[2] = { (tid & 3) * 8, (tid & 3) * 8 };   // (tid+512)&3 == tid&3

    __syncthreads();   // Wl/bl visible before FINALIZE(0)

    int wave = tid >> 6, lane = tid & 63, quad = lane >> 4, l16 = lane & 15;
    int wr = (wave >> 2) * 64, wc = (wave & 3) * 64;
    int kk = quad * 8;

    float4v acc[4][4];
#pragma unroll
    for (int mt = 0; mt < 4; ++mt)
#pragma unroll
        for (int nt = 0; nt < 4; ++nt) acc[mt][nt] = (float4v){0.f, 0.f, 0.f, 0.f};

    uint2 aRaw[2]; uint4 bRaw[2]; uint2 aWr[2];

    auto PREFETCH = [&](int kt) {
#pragma unroll
        for (int i = 0; i < 2; ++i) {
            const ushort_t* src = (kt < 8)
                ? peB + (size_t)kI[i] * 256 + kt * 32 + g4
                : f0B + (size_t)(row0 + rows2[i]) * 256 + (kt - 8) * 32 + g4;
            aRaw[i] = *(const uint2*)src;
        }
#pragma unroll
        for (int i = 0; i < 2; ++i)
            bRaw[i] = *(const uint4*)(PT + (size_t)bn[i] * 512 + kt * 32 + bo[i]);
    };
    auto FINALIZE = [&](int kt) {
        if (kt < 8) {
            int k0 = kt * 32 + g4;
            float4 w0 = *(const float4*)&Wl[k0];
            float4 w1 = *(const float4*)&Wl[256 + k0];
            float4 w2 = *(const float4*)&Wl[512 + k0];
            float4 bb = *(const float4*)&bl[k0];
#pragma unroll
            for (int i = 0; i < 2; ++i) {
                float dx = dxx[i], dy = dyy[i], dz = dzz[i];
                float v0 = lo2f(aRaw[i].x) + (fmaf(dz, w2.x, fmaf(dy, w1.x, dx * w0.x)) + bb.x);
                float v1 = hi2f(aRaw[i].x) + (fmaf(dz, w2.y, fmaf(dy, w1.y, dx * w0.y)) + bb.y);
                float v2 = lo2f(aRaw[i].y) + (fmaf(dz, w2.z, fmaf(dy, w1.z, dx * w0.z)) + bb.z);
                float v3 = hi2f(aRaw[i].y) + (fmaf(dz, w2.w, fmaf(dy, w1.w, dx * w0.w)) + bb.w);
                aWr[i].x = pk2(v0, v1);
                aWr[i].y = pk2(v2, v3);
            }
        } else {
            aWr[0] = aRaw[0];
            aWr[1] = aRaw[1];
        }
    };

    PREFETCH(0);
    FINALIZE(0);

    for (int kt = 0; kt < 16; ++kt) {
        int buf = kt & 1;
        ushort_t* Ab = A_lds + buf * (128 * 40);
        ushort_t* Bb = B_lds + buf * (256 * 40);
        *(uint2*)&Ab[rows2[0] * 40 + g4] = aWr[0];
        *(uint2*)&Ab[rows2[1] * 40 + g4] = aWr[1];
        *(uint4*)&Bb[bn[0] * 40 + bo[0]] = bRaw[0];
        *(uint4*)&Bb[bn[1] * 40 + bo[1]] = bRaw[1];
        __syncthreads();
        if (kt < 15) PREFETCH(kt + 1);

        short8 bfr[4];
#pragma unroll
        for (int nt = 0; nt < 4; ++nt)
            bfr[nt] = *(const short8*)&Bb[(wc + nt * 16 + l16) * 40 + kk];
#pragma unroll
        for (int mt = 0; mt < 4; ++mt) {
            short8 af = *(const short8*)&Ab[(wr + mt * 16 + l16) * 40 + kk];
#pragma unroll
            for (int nt = 0; nt < 4; ++nt)
                acc[mt][nt] = __builtin_amdgcn_mfma_f32_16x16x32_bf16(af, bfr[nt], acc[mt][nt], 0, 0, 0);
        }
        if (kt < 15) FINALIZE(kt + 1);
    }

    // epilogue: D row = quad*4+reg, col = lane&15
#pragma unroll
    for (int mt = 0; mt < 4; ++mt) {
#pragma unroll
        for (int nt = 0; nt < 4; ++nt) {
            int col = wc + nt * 16 + l16;
            float pbv = pb[col];
#pragma unroll
            for (int reg = 0; reg < 4; ++reg) {
                int row = row0 + wr + mt * 16 + quad * 4 + reg;
                size_t idx = (size_t)row * 256 + col;
                float val = acc[mt][nt][reg] + pbv;
                if (fp32out) ((float*)outv)[out_off + idx] = val;
                else         ((bf16*)outv)[out_off + idx] = __float2bfloat16(val);
                if (peOut) peOut[idx] = f2b(val);
            }
        }
    }
}

extern "C" void kernel_launch(void* const* d_in, const int* in_sizes, int n_in,
                              void* d_out, int out_size, void* d_ws, size_t ws_size,
                              hipStream_t stream) {
    const int* idx0 = (const int*)d_in[1];
    const int* idx1 = (const int*)d_in[2];
    const int* idx2 = (const int*)d_in[3];
    const int* idx3 = (const int*)d_in[4];
    const int* idx4 = (const int*)d_in[5];

    // workspace layout
    float* ws = (float*)d_ws;
    int* flag = (int*)ws;                 // 64 floats reserved
    float* p = ws + 64;
    float* xyzf = p;  p += 196608;
    float* Wallf = p; p += 768;
    float* ballf = p; p += 256;
    float* Wf[5]; float* bff[5];
    for (int i = 0; i < 5; ++i) { Wf[i] = p; p += 768; bff[i] = p; p += 256; }
    float* pbf[5];
    for (int i = 0; i < 5; ++i) { pbf[i] = p; p += 256; }
    int* k34 = (int*)p; p += 1024;
    int* k23 = (int*)p; p += 4096;
    int* k12 = (int*)p; p += 16384;
    ushort_t* PTb = (ushort_t*)p;                     // 5*131072
    ushort_t* cls4B = PTb + 5 * 131072;               // 256
    ushort_t* peB4 = cls4B + 256;                     // 256*256
    ushort_t* peB3 = peB4 + 256 * 256;                // 1024*256
    ushort_t* peB2 = peB3 + 1024 * 256;               // 4096*256
    ushort_t* peB1 = peB2 + 4096 * 256;               // 16384*256
    ushort_t* f0B  = peB1 + 16384 * 256;              // 65536*256

    detect_kernel<<<1, 256, 0, stream>>>((const unsigned short*)d_in[0], flag);

    CanonArgs ca;
    ca.src[0] = d_in[0];                      // xyz0
    ca.src[1] = d_in[6];                      // W_all
    ca.src[2] = d_in[7];                      // b_all
    for (int i = 0; i < 10; ++i) ca.src[3 + i] = d_in[8 + i];        // W4,b4..W0,b0
    ca.src[13] = d_in[19]; ca.src[14] = d_in[21]; ca.src[15] = d_in[23];
    ca.src[16] = d_in[25]; ca.src[17] = d_in[27];                    // pb4..pb0
    canon_kernel<<<798, 256, 0, stream>>>(ca, flag, ws + 64);

    PtArgs pa;
    pa.P[0] = d_in[18]; pa.P[1] = d_in[20]; pa.P[2] = d_in[22];
    pa.P[3] = d_in[24]; pa.P[4] = d_in[26];
    prep_pt<<<dim3(5, 8, 4), 256, 0, stream>>>(pa, flag, PTb);

    f0_prep<<<cN0 / 32, 256, 0, stream>>>(xyzf, Wallf, ballf, f0B);
    cls4_kernel<<<1, 256, 0, stream>>>(f0B, cls4B);
    nn_kernel<<<cN3 / 64, 256, 0, stream>>>(xyzf, idx3, idx4, cN4, k34);
    nn_kernel<<<cN2 / 64, 256, 0, stream>>>(xyzf, idx2, idx3, cN3, k23);
    nn_kernel<<<cN1 / 64, 256, 0, stream>>>(xyzf, idx1, idx2, cN2, k12);

    const size_t o4 = 0;
    const size_t o3 = (size_t)cN4 * 256;
    const size_t o2 = o3 + (size_t)cN3 * 256;
    const size_t o1 = o2 + (size_t)cN2 * 256;
    const size_t o0 = o1 + (size_t)cN1 * 256;

    level_mfma<<<cN4 / 128, 512, 0, stream>>>(
        xyzf, cls4B, f0B, nullptr, idx4, nullptr, Wf[0], bff[0],
        PTb + 0 * 131072, pbf[0], flag, d_out, o4, peB4);
    level_mfma<<<cN3 / 128, 512, 0, stream>>>(
        xyzf, peB4, f0B, k34, idx3, idx4, Wf[1], bff[1],
        PTb + 1 * 131072, pbf[1], flag, d_out, o3, peB3);
    level_mfma<<<cN2 / 128, 512, 0, stream>>>(
        xyzf, peB3, f0B, k23, idx2, idx3, Wf[2], bff[2],
        PTb + 2 * 131072, pbf[2], flag, d_out, o2, peB2);
    level_mfma<<<cN1 / 128, 512, 0, stream>>>(
        xyzf, peB2, f0B, k12, idx1, idx2, Wf[3], bff[3],
        PTb + 3 * 131072, pbf[3], flag, d_out, o1, peB1);
    level_mfma<<<cN0 / 128, 512, 0, stream>>>(
        xyzf, peB1, f0B, idx0, nullptr, idx1, Wf[4], bff[4],
        PTb + 4 * 131072, pbf[4], flag, d_out, o0, nullptr);
}